// Round 2
// baseline (345.793 us; speedup 1.0000x reference)
//
#include <hip/hip_runtime.h>
#include <stdint.h>

// STN forward: B=64, H=W=256, C=3; dense 196608->64->6; affine grid + bilinear.
constexpr int B_   = 64;
constexpr int H_   = 256;
constexpr int W_   = 256;
constexpr int C_   = 3;
constexpr int D_IN = H_ * W_ * C_;   // 196608
constexpr int D_H  = 64;
constexpr int KT   = 64;             // k-chunk per block
constexpr int NK   = D_IN / KT;      // 3072 blocks

__device__ __forceinline__ void gload_lds16(const void* g, void* l) {
    __builtin_amdgcn_global_load_lds(
        (const __attribute__((address_space(1))) void*)g,
        (__attribute__((address_space(3))) void*)l, 16, 0, 0);
}

__global__ void zero_kernel(float4* __restrict__ part4) {
    part4[blockIdx.x * 256 + threadIdx.x] = float4{0.f, 0.f, 0.f, 0.f};
}

// GEMM1: C(64x64) = A(64x196608) @ W1(196608x64). One 64-k chunk per block.
// 2 waves / 128 threads; wave w owns output cols [w*32, w*32+32).
// Per lane (ly=l>>3, lx=l&7): rows [8*ly, 8*ly+8), cols [w*32+lx*4, +4) -> acc[8][4].
// A tile LDS layout XOR-swizzled: chunk16' = chunk16 ^ ((row>>2)&7), applied on the
// global SOURCE address at stage time and on the LDS read (both-sides rule).
__global__ __launch_bounds__(128) void gemm1_kernel(
    const float* __restrict__ A, const float* __restrict__ W1,
    float* __restrict__ part, int s_mask)
{
    __shared__ float As[64 * 64];   // 16 KB, [row][kcol] 256B rows, swizzled chunks
    __shared__ float Ws[64 * 64];   // 16 KB, [k][col] linear

    const int tid = threadIdx.x;
    const int w   = tid >> 6;       // wave id 0/1
    const int l   = tid & 63;       // lane
    const int k0  = blockIdx.x * KT;

    // ---- async stage: wave0 -> A tile, wave1 -> W tile (16 x 1KB each) ----
    if (w == 0) {
#pragma unroll
        for (int m = 0; m < 16; ++m) {
            const int row = 4 * m + (l >> 4);              // 0..63
            const int c16 = (l & 15) ^ (m & 7);            // pre-swizzled source chunk
            gload_lds16(A + (size_t)row * D_IN + k0 + c16 * 4, As + m * 256);
        }
    } else {
#pragma unroll
        for (int m = 0; m < 16; ++m) {
            const int kr  = 4 * m + (l >> 4);              // k offset 0..63
            const int c16 = (l & 15);
            gload_lds16(W1 + (size_t)(k0 + kr) * D_H + c16 * 4, Ws + m * 256);
        }
    }
    asm volatile("s_waitcnt vmcnt(0)" ::: "memory");
    __syncthreads();

    // ---- compute ----
    const int ly = l >> 3, lx = l & 7;
    const int CB = w * 32 + lx * 4;                        // col base
    const float4* As4 = reinterpret_cast<const float4*>(As);
    const float4* Ws4 = reinterpret_cast<const float4*>(Ws);
    const int x0 = (2 * ly) & 7;                           // A-read swizzle for i<4 (^1 for i>=4)
    const int wcol = w * 8 + lx;                           // W float4-chunk within row

    float acc[8][4];
#pragma unroll
    for (int i = 0; i < 8; ++i)
#pragma unroll
        for (int j = 0; j < 4; ++j) acc[i][j] = 0.0f;

#pragma unroll 2
    for (int cc = 0; cc < 16; ++cc) {                      // k = 4*cc .. 4*cc+3
        float4 a[8];
#pragma unroll
        for (int i = 0; i < 8; ++i) {
            const int R = 8 * ly + i;
            const int sw = (i < 4) ? x0 : (x0 ^ 1);
            a[i] = As4[R * 16 + (cc ^ sw)];
        }
        float4 wf[4];
#pragma unroll
        for (int t = 0; t < 4; ++t)
            wf[t] = Ws4[(4 * cc + t) * 16 + wcol];
#pragma unroll
        for (int i = 0; i < 8; ++i) {
            acc[i][0] += a[i].x * wf[0].x + a[i].y * wf[1].x + a[i].z * wf[2].x + a[i].w * wf[3].x;
            acc[i][1] += a[i].x * wf[0].y + a[i].y * wf[1].y + a[i].z * wf[2].y + a[i].w * wf[3].y;
            acc[i][2] += a[i].x * wf[0].z + a[i].y * wf[1].z + a[i].z * wf[2].z + a[i].w * wf[3].z;
            acc[i][3] += a[i].x * wf[0].w + a[i].y * wf[1].w + a[i].z * wf[2].w + a[i].w * wf[3].w;
        }
    }

    // ---- split-K epilogue: atomics into partial buffer (blockIdx & s_mask) ----
    float* p = part + (size_t)(blockIdx.x & s_mask) * (B_ * D_H);
#pragma unroll
    for (int i = 0; i < 8; ++i)
#pragma unroll
        for (int j = 0; j < 4; ++j)
            atomicAdd(&p[(8 * ly + i) * D_H + CB + j], acc[i][j]);
}

// Reduce partials -> h = relu(.+b1); x2 = relu(h@W2+b2); mat = theta*x2. One block.
__global__ __launch_bounds__(256) void fc_tail_kernel(
    const float* __restrict__ part, int S,
    const float* __restrict__ b1, const float* __restrict__ W2,
    const float* __restrict__ b2, const float* __restrict__ theta,
    float* __restrict__ mat)
{
    __shared__ float h[B_][67];        // pad 67: phase-2 reads ~2-way conflict
    __shared__ float w2s[D_H * 6];
    __shared__ float pm[4][B_][8];
    const int t = threadIdx.x;

    for (int i = t; i < D_H * 6; i += 256) w2s[i] = W2[i];

    const float4* part4 = reinterpret_cast<const float4*>(part);
#pragma unroll
    for (int q = 0; q < 4; ++q) {
        const int c = q * 256 + t;     // float4 chunk 0..1023
        float4 sum = float4{0.f, 0.f, 0.f, 0.f};
        for (int s = 0; s < S; ++s) {
            float4 v = part4[s * 1024 + c];
            sum.x += v.x; sum.y += v.y; sum.z += v.z; sum.w += v.w;
        }
        const int base = c * 4;
        const int b = base >> 6, k = base & 63;
        h[b][k + 0] = fmaxf(sum.x + b1[k + 0], 0.f);
        h[b][k + 1] = fmaxf(sum.y + b1[k + 1], 0.f);
        h[b][k + 2] = fmaxf(sum.z + b1[k + 2], 0.f);
        h[b][k + 3] = fmaxf(sum.w + b1[k + 3], 0.f);
    }
    __syncthreads();

    const int b = t & 63, q = t >> 6;
    float p[6] = {0.f, 0.f, 0.f, 0.f, 0.f, 0.f};
    for (int kk = 0; kk < 16; ++kk) {
        const int k = q * 16 + kk;
        const float hv = h[b][k];
#pragma unroll
        for (int j = 0; j < 6; ++j) p[j] += hv * w2s[k * 6 + j];
    }
#pragma unroll
    for (int j = 0; j < 6; ++j) pm[q][b][j] = p[j];
    __syncthreads();

    if (t < B_) {
#pragma unroll
        for (int j = 0; j < 6; ++j) {
            float a = pm[0][t][j] + pm[1][t][j] + pm[2][t][j] + pm[3][t][j] + b2[j];
            mat[t * 6 + j] = theta[t * 6 + j] * fmaxf(a, 0.f);
        }
    }
}

// Affine grid + bilinear sample. 4 pixels per thread, 3x float4 coalesced stores.
__global__ __launch_bounds__(256) void sample_kernel(
    const float* __restrict__ img, const float* __restrict__ mat,
    float* __restrict__ out)
{
    const int b  = blockIdx.y;
    const int p0 = (blockIdx.x * 256 + threadIdx.x) * 4;   // first pixel of 4

    const float m00 = mat[b * 6 + 0], m01 = mat[b * 6 + 1], m02 = mat[b * 6 + 2];
    const float m10 = mat[b * 6 + 3], m11 = mat[b * 6 + 4], m12 = mat[b * 6 + 5];
    const float* base = img + (size_t)b * (H_ * W_ * C_);

    float res[12];
#pragma unroll
    for (int p = 0; p < 4; ++p) {
        const int pix = p0 + p;
        const int iy = pix >> 8, ix = pix & 255;
        const float step = 2.0f / 255.0f;
        const float xg = -1.0f + ix * step;
        const float yg = -1.0f + iy * step;
        const float xs = m00 * xg + m01 * yg + m02;
        const float ys = m10 * xg + m11 * yg + m12;
        const float xf = 0.5f * (xs + 1.0f) * 255.0f;
        const float yf = 0.5f * (ys + 1.0f) * 255.0f;
        const int x0 = (int)fminf(fmaxf(floorf(xf), 0.0f), 255.0f);
        const int y0 = (int)fminf(fmaxf(floorf(yf), 0.0f), 255.0f);
        const int x1 = min(x0 + 1, 255);
        const int y1 = min(y0 + 1, 255);
        const float wa = ((float)x1 - xf) * ((float)y1 - yf);
        const float wb = ((float)x1 - xf) * (yf - (float)y0);
        const float wc = (xf - (float)x0) * ((float)y1 - yf);
        const float wd = (xf - (float)x0) * (yf - (float)y0);
        const float* pa = base + (y0 * W_ + x0) * 3;
        const float* pb = base + (y1 * W_ + x0) * 3;
        const float* pc = base + (y0 * W_ + x1) * 3;
        const float* pd = base + (y1 * W_ + x1) * 3;
#pragma unroll
        for (int c = 0; c < 3; ++c)
            res[p * 3 + c] = wa * pa[c] + wb * pb[c] + wc * pc[c] + wd * pd[c];
    }

    float4* o4 = reinterpret_cast<float4*>(out + ((size_t)b * (H_ * W_) + p0) * 3);
    o4[0] = float4{res[0], res[1], res[2],  res[3]};
    o4[1] = float4{res[4], res[5], res[6],  res[7]};
    o4[2] = float4{res[8], res[9], res[10], res[11]};
}

extern "C" void kernel_launch(void* const* d_in, const int* in_sizes, int n_in,
                              void* d_out, int out_size, void* d_ws, size_t ws_size,
                              hipStream_t stream) {
    const float* inputs = (const float*)d_in[0];
    const float* W1     = (const float*)d_in[1];
    const float* b1     = (const float*)d_in[2];
    const float* W2     = (const float*)d_in[3];
    const float* b2     = (const float*)d_in[4];
    const float* theta  = (const float*)d_in[5];
    float* out = (float*)d_out;

    // S power-of-2 partial buffers (16 KB each), chosen deterministically from ws_size.
    int S = 1;
    const size_t resv = 8192;
    while (S < 16 && ws_size >= resv + (size_t)(S * 2) * (B_ * D_H) * sizeof(float)) S *= 2;

    float* part = (float*)d_ws;                 // S * 4096 floats
    float* mat  = part + (size_t)S * (B_ * D_H);

    zero_kernel<<<S * 4, 256, 0, stream>>>((float4*)part);
    gemm1_kernel<<<NK, 128, 0, stream>>>(inputs, W1, part, S - 1);
    fc_tail_kernel<<<1, 256, 0, stream>>>(part, S, b1, W2, b2, theta, mat);
    sample_kernel<<<dim3(H_ * W_ / 1024, B_), 256, 0, stream>>>(inputs, mat, out);
}

// Round 3
// 202.080 us; speedup vs baseline: 1.7112x; 1.7112x over previous
//
#include <hip/hip_runtime.h>
#include <stdint.h>

// STN forward: B=64, H=W=256, C=3; dense 196608->64->6; affine grid + bilinear.
constexpr int B_   = 64;
constexpr int H_   = 256;
constexpr int W_   = 256;
constexpr int C_   = 3;
constexpr int D_IN = H_ * W_ * C_;   // 196608
constexpr int D_H  = 64;
constexpr int KC   = 64;             // k per chunk
constexpr int CPP  = 3;              // chunks per wave-pair
constexpr int CPB  = 6;              // chunks per block (2 pairs)
constexpr int G1   = D_IN / (KC * CPB);  // 512 blocks

__device__ __forceinline__ void gload_lds16(const void* g, void* l) {
    __builtin_amdgcn_global_load_lds(
        (const __attribute__((address_space(1))) void*)g,
        (__attribute__((address_space(3))) void*)l, 16, 0, 0);
}

__global__ void zero_kernel(float4* __restrict__ part4) {
    part4[blockIdx.x * 256 + threadIdx.x] = float4{0.f, 0.f, 0.f, 0.f};
}

// GEMM1: C(64x64) = A(64x196608) @ W1(196608x64).
// 512 blocks x 256 thr (4 waves = 2 independent pairs). Pair p: 3 k-chunks of 64,
// private 32KB LDS (As swizzled + Ws). Within pair, wave lw owns cols [lw*32,+32).
// Epilogue: pair0 -> LDS scratch, pair1 adds, one atomic pass per block.
__global__ __launch_bounds__(256, 2) void gemm1_kernel(
    const float* __restrict__ A, const float* __restrict__ W1,
    float* __restrict__ part, int s_mask)
{
    __shared__ float lds[16384];     // 64 KB: [pair][As 4096 | Ws 4096]
    const int tid = threadIdx.x;
    const int w   = tid >> 6, l = tid & 63;
    const int p   = w >> 1, lw = w & 1;
    float* As = lds + p * 8192;
    float* Ws = As + 4096;
    const int ly = l >> 3, lx = l & 7;

    float acc[8][4];
#pragma unroll
    for (int i = 0; i < 8; ++i)
#pragma unroll
        for (int j = 0; j < 4; ++j) acc[i][j] = 0.0f;

    const int kbase = blockIdx.x * (KC * CPB) + p * (KC * CPP);
    const int x0    = (2 * ly) & 7;          // A-read swizzle base
    const int wcol  = lw * 8 + lx;           // W float4-chunk within k-row

    for (int t = 0; t < CPP; ++t) {
        const int k0 = kbase + t * KC;
        if (lw == 0) {                        // stage A tile (swizzled source)
#pragma unroll
            for (int m = 0; m < 16; ++m) {
                const int row = 4 * m + (l >> 4);
                const int c16 = (l & 15) ^ (m & 7);
                gload_lds16(A + (size_t)row * D_IN + k0 + c16 * 4, As + m * 256);
            }
        } else {                              // stage W tile (linear)
#pragma unroll
            for (int m = 0; m < 16; ++m) {
                const int kr = 4 * m + (l >> 4);
                gload_lds16(W1 + (size_t)(k0 + kr) * D_H + (l & 15) * 4, Ws + m * 256);
            }
        }
        asm volatile("s_waitcnt vmcnt(0)" ::: "memory");
        __syncthreads();

        const float4* As4 = reinterpret_cast<const float4*>(As);
        const float4* Ws4 = reinterpret_cast<const float4*>(Ws);
#pragma unroll 2
        for (int cc = 0; cc < 16; ++cc) {
            float4 a[8];
#pragma unroll
            for (int i = 0; i < 8; ++i) {
                const int R  = 8 * ly + i;
                const int sw = (i < 4) ? x0 : (x0 ^ 1);
                a[i] = As4[R * 16 + (cc ^ sw)];
            }
            float4 wf[4];
#pragma unroll
            for (int q = 0; q < 4; ++q)
                wf[q] = Ws4[(4 * cc + q) * 16 + wcol];
#pragma unroll
            for (int i = 0; i < 8; ++i) {
                acc[i][0] += a[i].x * wf[0].x + a[i].y * wf[1].x + a[i].z * wf[2].x + a[i].w * wf[3].x;
                acc[i][1] += a[i].x * wf[0].y + a[i].y * wf[1].y + a[i].z * wf[2].y + a[i].w * wf[3].y;
                acc[i][2] += a[i].x * wf[0].z + a[i].y * wf[1].z + a[i].z * wf[2].z + a[i].w * wf[3].z;
                acc[i][3] += a[i].x * wf[0].w + a[i].y * wf[1].w + a[i].z * wf[2].w + a[i].w * wf[3].w;
            }
        }
        __syncthreads();                      // protect LDS before next stage
    }

    // ---- pair combine + single atomic pass ----
    float4* scr = reinterpret_cast<float4*>(lds);   // overlays pair0 As (done)
    if (p == 0) {
#pragma unroll
        for (int i = 0; i < 8; ++i)
            scr[(8 * ly + i) * 16 + lw * 8 + lx] =
                float4{acc[i][0], acc[i][1], acc[i][2], acc[i][3]};
    }
    __syncthreads();
    if (p == 1) {
        float* dst = part + (size_t)(blockIdx.x & s_mask) * (B_ * D_H);
#pragma unroll
        for (int i = 0; i < 8; ++i) {
            const float4 o = scr[(8 * ly + i) * 16 + lw * 8 + lx];
            const int base = (8 * ly + i) * D_H + lw * 32 + lx * 4;
            atomicAdd(&dst[base + 0], acc[i][0] + o.x);
            atomicAdd(&dst[base + 1], acc[i][1] + o.y);
            atomicAdd(&dst[base + 2], acc[i][2] + o.z);
            atomicAdd(&dst[base + 3], acc[i][3] + o.w);
        }
    }
}

// Reduce S partials -> h = relu(.+b1); x2 = relu(h@W2+b2); mat = theta*x2.
__global__ __launch_bounds__(256) void fc_tail_kernel(
    const float* __restrict__ part, int S,
    const float* __restrict__ b1, const float* __restrict__ W2,
    const float* __restrict__ b2, const float* __restrict__ theta,
    float* __restrict__ mat)
{
    __shared__ float h[B_][67];
    __shared__ float w2s[D_H * 6];
    __shared__ float pm[4][B_][8];
    const int t = threadIdx.x;

    for (int i = t; i < D_H * 6; i += 256) w2s[i] = W2[i];

    const float4* part4 = reinterpret_cast<const float4*>(part);
#pragma unroll
    for (int q = 0; q < 4; ++q) {
        const int c = q * 256 + t;
        float4 sum = float4{0.f, 0.f, 0.f, 0.f};
        for (int s = 0; s < S; ++s) {
            float4 v = part4[s * 1024 + c];
            sum.x += v.x; sum.y += v.y; sum.z += v.z; sum.w += v.w;
        }
        const int base = c * 4;
        const int b = base >> 6, k = base & 63;
        h[b][k + 0] = fmaxf(sum.x + b1[k + 0], 0.f);
        h[b][k + 1] = fmaxf(sum.y + b1[k + 1], 0.f);
        h[b][k + 2] = fmaxf(sum.z + b1[k + 2], 0.f);
        h[b][k + 3] = fmaxf(sum.w + b1[k + 3], 0.f);
    }
    __syncthreads();

    const int b = t & 63, q = t >> 6;
    float pacc[6] = {0.f, 0.f, 0.f, 0.f, 0.f, 0.f};
    for (int kk = 0; kk < 16; ++kk) {
        const int k = q * 16 + kk;
        const float hv = h[b][k];
#pragma unroll
        for (int j = 0; j < 6; ++j) pacc[j] += hv * w2s[k * 6 + j];
    }
#pragma unroll
    for (int j = 0; j < 6; ++j) pm[q][b][j] = pacc[j];
    __syncthreads();

    if (t < B_) {
#pragma unroll
        for (int j = 0; j < 6; ++j) {
            float a = pm[0][t][j] + pm[1][t][j] + pm[2][t][j] + pm[3][t][j] + b2[j];
            mat[t * 6 + j] = theta[t * 6 + j] * fmaxf(a, 0.f);
        }
    }
}

// Affine grid + bilinear. Block = 4 output rows (1024 px) of one image.
// Stage the affine-bounded input box into LDS; gather from LDS (global fallback).
constexpr int TILE_CAP = 6144;   // floats (24 KB)

__global__ __launch_bounds__(256) void sample_kernel(
    const float* __restrict__ img, const float* __restrict__ mat,
    float* __restrict__ out)
{
    __shared__ float tile[TILE_CAP];
    const int b  = blockIdx.y;
    const int rb = blockIdx.x;                 // 4 output rows per block
    const int t  = threadIdx.x;

    const float m00 = mat[b * 6 + 0], m01 = mat[b * 6 + 1], m02 = mat[b * 6 + 2];
    const float m10 = mat[b * 6 + 3], m11 = mat[b * 6 + 4], m12 = mat[b * 6 + 5];
    const float* base = img + (size_t)b * (H_ * W_ * C_);
    const float step = 2.0f / 255.0f;

    // bounding box of sample coords over this block's grid region (affine -> corners)
    const float yg0 = -1.0f + (rb * 4 + 0) * step;
    const float yg1 = -1.0f + (rb * 4 + 3) * step;
    float xf00 = 0.5f * ((m00 * -1.f + m01 * yg0 + m02) + 1.f) * 255.f;
    float xf10 = 0.5f * ((m00 *  1.f + m01 * yg0 + m02) + 1.f) * 255.f;
    float xf01 = 0.5f * ((m00 * -1.f + m01 * yg1 + m02) + 1.f) * 255.f;
    float xf11 = 0.5f * ((m00 *  1.f + m01 * yg1 + m02) + 1.f) * 255.f;
    float yf00 = 0.5f * ((m10 * -1.f + m11 * yg0 + m12) + 1.f) * 255.f;
    float yf10 = 0.5f * ((m10 *  1.f + m11 * yg0 + m12) + 1.f) * 255.f;
    float yf01 = 0.5f * ((m10 * -1.f + m11 * yg1 + m12) + 1.f) * 255.f;
    float yf11 = 0.5f * ((m10 *  1.f + m11 * yg1 + m12) + 1.f) * 255.f;
    const float xfmin = fminf(fminf(xf00, xf10), fminf(xf01, xf11));
    const float xfmax = fmaxf(fmaxf(xf00, xf10), fmaxf(xf01, xf11));
    const float yfmin = fminf(fminf(yf00, yf10), fminf(yf01, yf11));
    const float yfmax = fmaxf(fmaxf(yf00, yf10), fmaxf(yf01, yf11));
    // +/-1 px fp-safety margin, clamp in float domain before int cast
    const int xlo = (int)fminf(fmaxf(floorf(xfmin) - 1.f, 0.f), 255.f);
    const int xhi = (int)fminf(fmaxf(floorf(xfmax) + 2.f, 0.f), 255.f);
    const int ylo = (int)fminf(fmaxf(floorf(yfmin) - 1.f, 0.f), 255.f);
    const int yhi = (int)fminf(fmaxf(floorf(yfmax) + 2.f, 0.f), 255.f);
    const int wb = xhi - xlo + 1, hb = yhi - ylo + 1;
    const int w3 = wb * 3;
    const bool fits = (hb * w3 <= TILE_CAP);

    if (fits) {
        const int total = hb * w3;
        for (int i = t; i < total; i += 256) {
            const int r = i / w3, c = i - r * w3;
            tile[i] = base[((ylo + r) * W_ + xlo) * 3 + c];
        }
    }
    __syncthreads();

    const int p0 = rb * 1024 + t * 4;
    float res[12];
#pragma unroll
    for (int pp = 0; pp < 4; ++pp) {
        const int pix = p0 + pp;
        const int iy = pix >> 8, ix = pix & 255;
        const float xg = -1.0f + ix * step;
        const float yg = -1.0f + iy * step;
        const float xs = m00 * xg + m01 * yg + m02;
        const float ys = m10 * xg + m11 * yg + m12;
        const float xf = 0.5f * (xs + 1.0f) * 255.0f;
        const float yf = 0.5f * (ys + 1.0f) * 255.0f;
        const int x0 = (int)fminf(fmaxf(floorf(xf), 0.0f), 255.0f);
        const int y0 = (int)fminf(fmaxf(floorf(yf), 0.0f), 255.0f);
        const int x1 = min(x0 + 1, 255);
        const int y1 = min(y0 + 1, 255);
        const float wa = ((float)x1 - xf) * ((float)y1 - yf);
        const float wwb = ((float)x1 - xf) * (yf - (float)y0);
        const float wc = (xf - (float)x0) * ((float)y1 - yf);
        const float wd = (xf - (float)x0) * (yf - (float)y0);
        if (fits) {
            const float* pa = &tile[((y0 - ylo) * wb + (x0 - xlo)) * 3];
            const float* pb = &tile[((y1 - ylo) * wb + (x0 - xlo)) * 3];
            const float* pc = &tile[((y0 - ylo) * wb + (x1 - xlo)) * 3];
            const float* pd = &tile[((y1 - ylo) * wb + (x1 - xlo)) * 3];
#pragma unroll
            for (int c = 0; c < 3; ++c)
                res[pp * 3 + c] = wa * pa[c] + wwb * pb[c] + wc * pc[c] + wd * pd[c];
        } else {
            const float* pa = base + (y0 * W_ + x0) * 3;
            const float* pb = base + (y1 * W_ + x0) * 3;
            const float* pc = base + (y0 * W_ + x1) * 3;
            const float* pd = base + (y1 * W_ + x1) * 3;
#pragma unroll
            for (int c = 0; c < 3; ++c)
                res[pp * 3 + c] = wa * pa[c] + wwb * pb[c] + wc * pc[c] + wd * pd[c];
        }
    }

    float4* o4 = reinterpret_cast<float4*>(out + ((size_t)b * (H_ * W_) + p0) * 3);
    o4[0] = float4{res[0], res[1], res[2],  res[3]};
    o4[1] = float4{res[4], res[5], res[6],  res[7]};
    o4[2] = float4{res[8], res[9], res[10], res[11]};
}

extern "C" void kernel_launch(void* const* d_in, const int* in_sizes, int n_in,
                              void* d_out, int out_size, void* d_ws, size_t ws_size,
                              hipStream_t stream) {
    const float* inputs = (const float*)d_in[0];
    const float* W1     = (const float*)d_in[1];
    const float* b1     = (const float*)d_in[2];
    const float* W2     = (const float*)d_in[3];
    const float* b2     = (const float*)d_in[4];
    const float* theta  = (const float*)d_in[5];
    float* out = (float*)d_out;

    // S power-of-2 partial buffers (16 KB each), deterministic from ws_size, cap 8.
    int S = 1;
    const size_t resv = 8192;
    while (S < 8 && ws_size >= resv + (size_t)(S * 2) * (B_ * D_H) * sizeof(float)) S *= 2;

    float* part = (float*)d_ws;
    float* mat  = part + (size_t)S * (B_ * D_H);

    zero_kernel<<<S * 4, 256, 0, stream>>>((float4*)part);
    gemm1_kernel<<<G1, 256, 0, stream>>>(inputs, W1, part, S - 1);
    fc_tail_kernel<<<1, 256, 0, stream>>>(part, S, b1, W2, b2, theta, mat);
    sample_kernel<<<dim3(H_ * W_ / 1024, B_), 256, 0, stream>>>(inputs, mat, out);
}

// Round 4
// 188.863 us; speedup vs baseline: 1.8309x; 1.0700x over previous
//
#include <hip/hip_runtime.h>
#include <stdint.h>

// STN forward: B=64, H=W=256, C=3; dense 196608->64->6; affine grid + bilinear.
constexpr int B_   = 64;
constexpr int H_   = 256;
constexpr int W_   = 256;
constexpr int C_   = 3;
constexpr int D_IN = H_ * W_ * C_;   // 196608
constexpr int D_H  = 64;
constexpr int KC   = 16;             // k per chunk
constexpr int NCH  = D_IN / KC;      // 12288 chunks
constexpr int CPW  = 6;              // chunks per wave
constexpr int NB   = NCH / (4 * CPW); // 512 blocks (4 waves each)

__device__ __forceinline__ void gload_lds16(const float* g, float* l) {
    __builtin_amdgcn_global_load_lds(
        (const __attribute__((address_space(1))) void*)g,
        (__attribute__((address_space(3))) void*)l, 16, 0, 0);
}

__global__ void zero_kernel(float4* __restrict__ p4) {
    p4[blockIdx.x * 256 + threadIdx.x] = float4{0.f, 0.f, 0.f, 0.f};
}

// GEMM1: C(64x64) = A(64x196608) @ W1(196608x64).
// 512 blocks x 4 waves. Each wave owns the FULL 64x64 C tile for its own
// 6x16-k chunk stream: wave-private LDS (dbuf As 4K + Ws 4K), NO barriers in
// the k-loop — counted vmcnt(8) only. Per lane: 8x8 acc (rows 8ly.., cols 8lx..).
// A-tile k-quad XOR-swizzled by (row>>3)&3, pre-swizzled at the global source.
// Epilogue: 4-wave LDS reduce -> coalesced stores (STORE=1) or atomics (=0).
template<int STORE>
__global__ __launch_bounds__(256, 2) void gemm1_kernel(
    const float* __restrict__ A, const float* __restrict__ W1,
    float* __restrict__ part, int s_mask)
{
    __shared__ float lds[16384];          // 64 KB: wave w -> lds[w*4096 ..)
    const int tid = threadIdx.x;
    const int w = tid >> 6, l = tid & 63;
    const int ly = l >> 3, lx = l & 7;
    float* WB = lds + w * 4096;           // [buf][As 1024f | Ws 1024f]

    const int arow_l = l >> 2;            // A stage: row-within-16
    const int aq_l   = l & 3;             // A stage: dest quad slot
    const int wkr_l  = l >> 4;            // W stage: k-within-4
    const int wc4_l  = l & 15;            // W stage: col quad

    const int gw    = blockIdx.x * 4 + w;
    const int kbase = gw * (CPW * KC);

    float acc[8][8];
#pragma unroll
    for (int i = 0; i < 8; ++i)
#pragma unroll
        for (int j = 0; j < 8; ++j) acc[i][j] = 0.f;

    auto stage = [&](int buf, int t) {
        const int k0 = kbase + t * KC;
        float* As = WB + buf * 2048;
        float* Ws = As + 1024;
#pragma unroll
        for (int m = 0; m < 4; ++m) {     // A: 16 rows x 16 floats per instr
            const int row = 16 * m + arow_l;
            const int q   = aq_l ^ ((row >> 3) & 3);       // pre-swizzled src
            gload_lds16(A + (size_t)row * D_IN + k0 + 4 * q, As + m * 256);
        }
#pragma unroll
        for (int m = 0; m < 4; ++m) {     // W: 4 k-rows x 64 cols per instr
            const int kr = 4 * m + wkr_l;
            gload_lds16(W1 + (size_t)(k0 + kr) * D_H + 4 * wc4_l, Ws + m * 256);
        }
    };

    stage(0, 0);
    for (int t = 0; t < CPW; ++t) {
        if (t + 1 < CPW) {
            stage((t + 1) & 1, t + 1);
            asm volatile("s_waitcnt vmcnt(8)" ::: "memory");   // prev chunk done
        } else {
            asm volatile("s_waitcnt vmcnt(0)" ::: "memory");
        }
        __builtin_amdgcn_sched_barrier(0);
        const float4* As4 = (const float4*)(WB + (t & 1) * 2048);
        const float4* Ws4 = As4 + 256;
#pragma unroll
        for (int cc = 0; cc < 4; ++cc) {
            float4 a[8];
#pragma unroll
            for (int i = 0; i < 8; ++i)
                a[i] = As4[(8 * ly + i) * 4 + (cc ^ (ly & 3))];  // swizzled read
#pragma unroll
            for (int q = 0; q < 4; ++q) {
                const float4 w0 = Ws4[(4 * cc + q) * 16 + 2 * lx];
                const float4 w1 = Ws4[(4 * cc + q) * 16 + 2 * lx + 1];
#pragma unroll
                for (int i = 0; i < 8; ++i) {
                    const float aq = (q == 0) ? a[i].x : (q == 1) ? a[i].y
                                   : (q == 2) ? a[i].z : a[i].w;
                    acc[i][0] += aq * w0.x; acc[i][1] += aq * w0.y;
                    acc[i][2] += aq * w0.z; acc[i][3] += aq * w0.w;
                    acc[i][4] += aq * w1.x; acc[i][5] += aq * w1.y;
                    acc[i][6] += aq * w1.z; acc[i][7] += aq * w1.w;
                }
            }
        }
    }

    // ---- epilogue: dump acc to wave region, 4-wave reduce, store/atomic ----
    float4* R = (float4*)(lds + w * 4096);
#pragma unroll
    for (int i = 0; i < 8; ++i) {
        R[(8 * ly + i) * 16 + 2 * lx]     = float4{acc[i][0], acc[i][1], acc[i][2], acc[i][3]};
        R[(8 * ly + i) * 16 + 2 * lx + 1] = float4{acc[i][4], acc[i][5], acc[i][6], acc[i][7]};
    }
    __syncthreads();
    const float4* L4 = (const float4*)lds;
#pragma unroll
    for (int j = 0; j < 4; ++j) {
        const int idx = j * 256 + tid;    // f4 index 0..1023
        const float4 s0 = L4[idx],        s1 = L4[1024 + idx];
        const float4 s2 = L4[2048 + idx], s3 = L4[3072 + idx];
        const float4 r{s0.x + s1.x + s2.x + s3.x, s0.y + s1.y + s2.y + s3.y,
                       s0.z + s1.z + s2.z + s3.z, s0.w + s1.w + s2.w + s3.w};
        if (STORE) {
            ((float4*)part)[(size_t)blockIdx.x * 1024 + idx] = r;
        } else {
            float* dst = part + (size_t)(blockIdx.x & s_mask) * 4096 + idx * 4;
            atomicAdd(dst + 0, r.x); atomicAdd(dst + 1, r.y);
            atomicAdd(dst + 2, r.z); atomicAdd(dst + 3, r.w);
        }
    }
}

// Sum 512 partials -> 8 slice-partials (consumed by fc_tail with S=8).
__global__ __launch_bounds__(256) void reduce_kernel(
    const float* __restrict__ part, float* __restrict__ out1)
{
    const int slice = blockIdx.x >> 4;          // 0..7 (64 partials each)
    const int i     = (blockIdx.x & 15) * 256 + threadIdx.x;   // 0..4095
    const float* p  = part + (size_t)slice * 64 * 4096 + i;
    float s = 0.f;
    for (int ss = 0; ss < 64; ++ss) s += p[ss * 4096];
    out1[slice * 4096 + i] = s;
}

// Reduce S partials -> h = relu(.+b1); x2 = relu(h@W2+b2); mat = theta*x2.
__global__ __launch_bounds__(256) void fc_tail_kernel(
    const float* __restrict__ part, int S,
    const float* __restrict__ b1, const float* __restrict__ W2,
    const float* __restrict__ b2, const float* __restrict__ theta,
    float* __restrict__ mat)
{
    __shared__ float h[B_][67];
    __shared__ float w2s[D_H * 6];
    __shared__ float pm[4][B_][8];
    const int t = threadIdx.x;

    for (int i = t; i < D_H * 6; i += 256) w2s[i] = W2[i];

    const float4* part4 = reinterpret_cast<const float4*>(part);
#pragma unroll
    for (int q = 0; q < 4; ++q) {
        const int c = q * 256 + t;
        float4 sum = float4{0.f, 0.f, 0.f, 0.f};
        for (int s = 0; s < S; ++s) {
            float4 v = part4[s * 1024 + c];
            sum.x += v.x; sum.y += v.y; sum.z += v.z; sum.w += v.w;
        }
        const int base = c * 4;
        const int b = base >> 6, k = base & 63;
        h[b][k + 0] = fmaxf(sum.x + b1[k + 0], 0.f);
        h[b][k + 1] = fmaxf(sum.y + b1[k + 1], 0.f);
        h[b][k + 2] = fmaxf(sum.z + b1[k + 2], 0.f);
        h[b][k + 3] = fmaxf(sum.w + b1[k + 3], 0.f);
    }
    __syncthreads();

    const int b = t & 63, q = t >> 6;
    float pacc[6] = {0.f, 0.f, 0.f, 0.f, 0.f, 0.f};
    for (int kk = 0; kk < 16; ++kk) {
        const int k = q * 16 + kk;
        const float hv = h[b][k];
#pragma unroll
        for (int j = 0; j < 6; ++j) pacc[j] += hv * w2s[k * 6 + j];
    }
#pragma unroll
    for (int j = 0; j < 6; ++j) pm[q][b][j] = pacc[j];
    __syncthreads();

    if (t < B_) {
#pragma unroll
        for (int j = 0; j < 6; ++j) {
            float a = pm[0][t][j] + pm[1][t][j] + pm[2][t][j] + pm[3][t][j] + b2[j];
            mat[t * 6 + j] = theta[t * 6 + j] * fmaxf(a, 0.f);
        }
    }
}

// Affine grid + bilinear. Block = 4 output rows (1024 px) of one image.
// RGBX float4 LDS tile of the affine-bounded box: each corner = 1 ds_read_b128.
constexpr int TCAP = 2048;   // pixels (32 KB RGBX)

__global__ __launch_bounds__(256) void sample_kernel(
    const float* __restrict__ img, const float* __restrict__ mat,
    float* __restrict__ out)
{
    __shared__ float4 tile[TCAP];
    const int b  = blockIdx.y;
    const int rb = blockIdx.x;
    const int t  = threadIdx.x;

    const float m00 = mat[b * 6 + 0], m01 = mat[b * 6 + 1], m02 = mat[b * 6 + 2];
    const float m10 = mat[b * 6 + 3], m11 = mat[b * 6 + 4], m12 = mat[b * 6 + 5];
    const float* base = img + (size_t)b * (H_ * W_ * C_);
    const float step = 2.0f / 255.0f;

    // bounding box of sample coords over this block's 4 rows (affine -> corners)
    const float yg0 = -1.0f + (rb * 4 + 0) * step;
    const float yg1 = -1.0f + (rb * 4 + 3) * step;
    const float xf00 = 0.5f * ((m00 * -1.f + m01 * yg0 + m02) + 1.f) * 255.f;
    const float xf10 = 0.5f * ((m00 *  1.f + m01 * yg0 + m02) + 1.f) * 255.f;
    const float xf01 = 0.5f * ((m00 * -1.f + m01 * yg1 + m02) + 1.f) * 255.f;
    const float xf11 = 0.5f * ((m00 *  1.f + m01 * yg1 + m02) + 1.f) * 255.f;
    const float yf00 = 0.5f * ((m10 * -1.f + m11 * yg0 + m12) + 1.f) * 255.f;
    const float yf10 = 0.5f * ((m10 *  1.f + m11 * yg0 + m12) + 1.f) * 255.f;
    const float yf01 = 0.5f * ((m10 * -1.f + m11 * yg1 + m12) + 1.f) * 255.f;
    const float yf11 = 0.5f * ((m10 *  1.f + m11 * yg1 + m12) + 1.f) * 255.f;
    const float xfmin = fminf(fminf(xf00, xf10), fminf(xf01, xf11));
    const float xfmax = fmaxf(fmaxf(xf00, xf10), fmaxf(xf01, xf11));
    const float yfmin = fminf(fminf(yf00, yf10), fminf(yf01, yf11));
    const float yfmax = fmaxf(fmaxf(yf00, yf10), fmaxf(yf01, yf11));
    const int xlo = (int)fminf(fmaxf(floorf(xfmin) - 1.f, 0.f), 255.f);
    const int xhi = (int)fminf(fmaxf(floorf(xfmax) + 2.f, 0.f), 255.f);
    const int ylo = (int)fminf(fmaxf(floorf(yfmin) - 1.f, 0.f), 255.f);
    const int yhi = (int)fminf(fmaxf(floorf(yfmax) + 2.f, 0.f), 255.f);
    const int wb = xhi - xlo + 1, hb = yhi - ylo + 1;
    const bool fits = (wb * hb <= TCAP);

    if (fits) {                           // stage box as RGBX
        for (int r = t >> 5; r < hb; r += 8) {
            const float* src = base + ((ylo + r) * W_ + xlo) * 3;
            for (int c = t & 31; c < wb; c += 32)
                tile[r * wb + c] = float4{src[c * 3], src[c * 3 + 1], src[c * 3 + 2], 0.f};
        }
    }
    __syncthreads();

    const int p0 = rb * 1024 + t * 4;
    float res[12];
#pragma unroll
    for (int pp = 0; pp < 4; ++pp) {
        const int pix = p0 + pp;
        const int iy = pix >> 8, ix = pix & 255;
        const float xg = -1.0f + ix * step;
        const float yg = -1.0f + iy * step;
        const float xf = 0.5f * ((m00 * xg + m01 * yg + m02) + 1.0f) * 255.0f;
        const float yf = 0.5f * ((m10 * xg + m11 * yg + m12) + 1.0f) * 255.0f;
        const int x0 = (int)fminf(fmaxf(floorf(xf), 0.0f), 255.0f);
        const int y0 = (int)fminf(fmaxf(floorf(yf), 0.0f), 255.0f);
        const int x1 = min(x0 + 1, 255);
        const int y1 = min(y0 + 1, 255);
        const float wa  = ((float)x1 - xf) * ((float)y1 - yf);
        const float wwb = ((float)x1 - xf) * (yf - (float)y0);
        const float wc  = (xf - (float)x0) * ((float)y1 - yf);
        const float wd  = (xf - (float)x0) * (yf - (float)y0);
        float4 A4, B4, C4, D4;
        if (fits) {
            A4 = tile[(y0 - ylo) * wb + (x0 - xlo)];
            B4 = tile[(y1 - ylo) * wb + (x0 - xlo)];
            C4 = tile[(y0 - ylo) * wb + (x1 - xlo)];
            D4 = tile[(y1 - ylo) * wb + (x1 - xlo)];
        } else {
            const float* pa = base + (y0 * W_ + x0) * 3;
            const float* pb = base + (y1 * W_ + x0) * 3;
            const float* pc = base + (y0 * W_ + x1) * 3;
            const float* pd = base + (y1 * W_ + x1) * 3;
            A4 = float4{pa[0], pa[1], pa[2], 0.f};
            B4 = float4{pb[0], pb[1], pb[2], 0.f};
            C4 = float4{pc[0], pc[1], pc[2], 0.f};
            D4 = float4{pd[0], pd[1], pd[2], 0.f};
        }
        res[pp * 3 + 0] = wa * A4.x + wwb * B4.x + wc * C4.x + wd * D4.x;
        res[pp * 3 + 1] = wa * A4.y + wwb * B4.y + wc * C4.y + wd * D4.y;
        res[pp * 3 + 2] = wa * A4.z + wwb * B4.z + wc * C4.z + wd * D4.z;
    }

    float4* o4 = reinterpret_cast<float4*>(out + ((size_t)b * (H_ * W_) + p0) * 3);
    o4[0] = float4{res[0], res[1], res[2],  res[3]};
    o4[1] = float4{res[4], res[5], res[6],  res[7]};
    o4[2] = float4{res[8], res[9], res[10], res[11]};
}

extern "C" void kernel_launch(void* const* d_in, const int* in_sizes, int n_in,
                              void* d_out, int out_size, void* d_ws, size_t ws_size,
                              hipStream_t stream) {
    const float* inputs = (const float*)d_in[0];
    const float* W1     = (const float*)d_in[1];
    const float* b1     = (const float*)d_in[2];
    const float* W2     = (const float*)d_in[3];
    const float* b2     = (const float*)d_in[4];
    const float* theta  = (const float*)d_in[5];
    float* out = (float*)d_out;

    // ws layout: [0,384B) mat | @1KB out1 (8x4096 f) | @132KB part (512x4096 f)
    float* mat  = (float*)d_ws;
    float* out1 = (float*)d_ws + 256;
    float* part = out1 + 8 * 4096;
    const size_t need = (256 + 8 * 4096 + (size_t)NB * 4096) * sizeof(float);

    if (ws_size >= need) {
        gemm1_kernel<1><<<NB, 256, 0, stream>>>(inputs, W1, part, 0);
        reduce_kernel<<<128, 256, 0, stream>>>(part, out1);
        fc_tail_kernel<<<1, 256, 0, stream>>>(out1, 8, b1, W2, b2, theta, mat);
    } else {
        int S = 1;
        while (S < 8 && ws_size >= (256 + (size_t)S * 2 * 4096) * sizeof(float)) S *= 2;
        zero_kernel<<<S * 4, 256, 0, stream>>>((float4*)out1);
        gemm1_kernel<0><<<NB, 256, 0, stream>>>(inputs, W1, out1, S - 1);
        fc_tail_kernel<<<1, 256, 0, stream>>>(out1, S, b1, W2, b2, theta, mat);
    }
    sample_kernel<<<dim3(64, 64), 256, 0, stream>>>(inputs, mat, out);
}